// Round 2
// baseline (507.241 us; speedup 1.0000x reference)
//
#include <hip/hip_runtime.h>
#include <hip/hip_bf16.h>

using bf16 = __hip_bfloat16;
typedef __attribute__((ext_vector_type(8))) short short8;
typedef __attribute__((ext_vector_type(4))) float f32x4;

__device__ __forceinline__ float b2f(bf16 x){ return __bfloat162float(x); }
__device__ __forceinline__ bf16  f2b(float x){ return __float2bfloat16(x); }

__device__ __forceinline__ void gload_lds16(const void* g, void* l){
  __builtin_amdgcn_global_load_lds((const __attribute__((address_space(1))) unsigned int*)g,
                                   (__attribute__((address_space(3))) unsigned int*)l, 16, 0, 0);
}

// ---------------- transpose f32 [R,C] -> bf16 [C,R] ----------------
__global__ __launch_bounds__(256) void transpose_k(const float* __restrict__ in,
                                                   bf16* __restrict__ out, int R, int C){
  __shared__ bf16 tile[32][33];
  int bx = blockIdx.x*32, by = blockIdx.y*32;
  int tx = threadIdx.x, ty = threadIdx.y;
  #pragma unroll
  for (int i=0;i<32;i+=8) tile[ty+i][tx] = f2b(in[(size_t)(by+ty+i)*C + bx+tx]);
  __syncthreads();
  #pragma unroll
  for (int i=0;i<32;i+=8) out[(size_t)(bx+ty+i)*R + by+tx] = tile[tx][ty+i];
}

// ---------------- layernorm: row of 1024 f32 -> bf16, block=256 ----------------
__global__ __launch_bounds__(256) void ln_k(const float* __restrict__ in, const float* __restrict__ w,
                                            const float* __restrict__ b, bf16* __restrict__ out){
  int row = blockIdx.x, t = threadIdx.x;
  const float* rp = in + (size_t)row*1024;
  float xv[4]; float s = 0.f, s2 = 0.f;
  #pragma unroll
  for (int j=0;j<4;++j){ float x = rp[t + j*256]; xv[j]=x; s+=x; s2+=x*x; }
  #pragma unroll
  for (int d=1; d<64; d<<=1){ s += __shfl_xor(s,d,64); s2 += __shfl_xor(s2,d,64); }
  __shared__ float sb[8];
  if ((t&63)==0){ sb[t>>6]=s; sb[4+(t>>6)]=s2; }
  __syncthreads();
  s = sb[0]+sb[1]+sb[2]+sb[3]; s2 = sb[4]+sb[5]+sb[6]+sb[7];
  float mu = s*(1.f/1024.f);
  float var = s2*(1.f/1024.f) - mu*mu;
  float rs = rsqrtf(var + 1e-5f);
  #pragma unroll
  for (int j=0;j<4;++j){
    int c = t + j*256;
    out[(size_t)row*1024 + c] = f2b((xv[j]-mu)*rs*w[c] + b[c]);
  }
}

// ---------------- GEMM: C[M,N] = A[M,K] @ Bt[N,K]^T + bias (+epi) ----------------
// EPI: 0 = bias -> bf16 out
//      1 = bias + exact GELU -> bf16 out
//      2 = bias + f32 residual -> f32 out
template<int EPI>
__global__ __launch_bounds__(256) void gemm_bt(const bf16* __restrict__ A, const bf16* __restrict__ Bt,
                                               const float* __restrict__ bias, const float* __restrict__ res,
                                               void* __restrict__ Cp, int M, int N, int K){
  __shared__ bf16 As[128*32];
  __shared__ bf16 Bs[128*32];
  const int bm = blockIdx.y*128, bn = blockIdx.x*128;
  const int t = threadIdx.x, lane = t & 63;
  const int wr = ((t>>6)>>1)*64, wc = ((t>>6)&1)*64;
  const int lrow = lane & 15, lko = (lane>>4)*8;
  f32x4 acc[4][4] = {};

  for (int k0 = 0; k0 < K; k0 += 32){
    __syncthreads();
    #pragma unroll
    for (int it=0; it<2; ++it){
      int o = t*16 + it*4096;          // byte offset within 8 KB tile
      int row = o >> 6;                // 64 B per row (32 bf16)
      int cole = (o & 63) >> 1;        // element col
      const bf16* ga = A  + (size_t)(bm+row)*K + k0 + cole;
      const bf16* gb = Bt + (size_t)(bn+row)*K + k0 + cole;
      unsigned lbase = (unsigned)((t>>6)*1024 + it*4096);
      gload_lds16(ga, (char*)As + lbase);
      gload_lds16(gb, (char*)Bs + lbase);
    }
    __syncthreads();
    short8 af[4], bfr[4];
    #pragma unroll
    for (int m=0;m<4;++m) af[m]  = *(const short8*)&As[(wr + m*16 + lrow)*32 + lko];
    #pragma unroll
    for (int n=0;n<4;++n) bfr[n] = *(const short8*)&Bs[(wc + n*16 + lrow)*32 + lko];
    #pragma unroll
    for (int m=0;m<4;++m)
      #pragma unroll
      for (int n=0;n<4;++n)
        acc[m][n] = __builtin_amdgcn_mfma_f32_16x16x32_bf16(af[m], bfr[n], acc[m][n], 0,0,0);
  }

  #pragma unroll
  for (int m=0;m<4;++m){
    int rowb = bm + wr + m*16 + ((lane>>4)<<2);
    #pragma unroll
    for (int n=0;n<4;++n){
      int col = bn + wc + n*16 + (lane&15);
      float bv = bias[col];
      #pragma unroll
      for (int r=0;r<4;++r){
        size_t idx = (size_t)(rowb+r)*N + col;
        float vv = acc[m][n][r] + bv;
        if constexpr (EPI==1) vv = 0.5f*vv*(1.f + erff(vv*0.70710678118f));
        if constexpr (EPI==2){ vv += res[idx]; ((float*)Cp)[idx] = vv; }
        else ((bf16*)Cp)[idx] = f2b(vv);
      }
    }
  }
}

// ---------------- flash attention: grid (32 qtiles, 16 heads, 2 batch) ----------------
__global__ __launch_bounds__(256) void attn_k(const bf16* __restrict__ q, const bf16* __restrict__ k,
                                              const bf16* __restrict__ v, bf16* __restrict__ o){
  const int C = 1024;
  int qt = blockIdx.x, h = blockIdx.y, b = blockIdx.z;
  int t = threadIdx.x, lane = t & 63, w = t >> 6;
  int lrow = lane & 15, g = lane >> 4, lko = g*8;
  __shared__ bf16 Vt[64*32];      // [d][key] transposed V tile
  __shared__ bf16 Pl[4][16*32];   // per-wave P buffer

  size_t qrow = (size_t)(b*2048 + qt*64 + w*16 + lrow);
  short8 qf0 = *(const short8*)(q + qrow*C + h*64 + lko);
  short8 qf1 = *(const short8*)(q + qrow*C + h*64 + 32 + lko);

  float mrun[4] = {-1e30f,-1e30f,-1e30f,-1e30f};
  float lrun[4] = {0.f,0.f,0.f,0.f};
  f32x4 oacc[4] = {};

  const bf16* kbase = k + (size_t)b*2048*C + h*64;
  const bf16* vbase = v + (size_t)b*2048*C + h*64;

  for (int kt = 0; kt < 2048; kt += 32){
    __syncthreads();
    { // stage V tile transposed: 8 lanes cover one key row (128 B contiguous)
      int key = t >> 3, d0 = (t & 7)*8;
      short8 vv = *(const short8*)(vbase + (size_t)(kt+key)*C + d0);
      #pragma unroll
      for (int j=0;j<8;++j) Vt[(d0+j)*32 + key] = ((const bf16*)&vv)[j];
    }
    __syncthreads();

    f32x4 s[2];
    #pragma unroll
    for (int cb=0; cb<2; ++cb){
      const bf16* kp = kbase + (size_t)(kt + cb*16 + lrow)*C;
      short8 kf0 = *(const short8*)(kp + lko);
      short8 kf1 = *(const short8*)(kp + 32 + lko);
      f32x4 a = {};
      a = __builtin_amdgcn_mfma_f32_16x16x32_bf16(qf0, kf0, a, 0,0,0);
      a = __builtin_amdgcn_mfma_f32_16x16x32_bf16(qf1, kf1, a, 0,0,0);
      s[cb] = a * 0.125f;   // 1/sqrt(64)
    }

    float ps0[4], ps1[4];
    #pragma unroll
    for (int r=0;r<4;++r){
      float mx = fmaxf(s[0][r], s[1][r]);
      #pragma unroll
      for (int d=1; d<16; d<<=1) mx = fmaxf(mx, __shfl_xor(mx, d, 64));
      float mnew = fmaxf(mrun[r], mx);
      float al = __expf(mrun[r] - mnew);
      mrun[r] = mnew;
      ps0[r] = __expf(s[0][r] - mnew);
      ps1[r] = __expf(s[1][r] - mnew);
      float sm = ps0[r] + ps1[r];
      #pragma unroll
      for (int d=1; d<16; d<<=1) sm += __shfl_xor(sm, d, 64);
      lrun[r] = lrun[r]*al + sm;
      #pragma unroll
      for (int db=0; db<4; ++db) oacc[db][r] *= al;
      Pl[w][(g*4+r)*32 + lrow]      = f2b(ps0[r]);
      Pl[w][(g*4+r)*32 + 16 + lrow] = f2b(ps1[r]);
    }

    short8 pf = *(const short8*)&Pl[w][lrow*32 + lko];
    #pragma unroll
    for (int db=0; db<4; ++db){
      short8 vf = *(const short8*)&Vt[(db*16 + lrow)*32 + lko];
      oacc[db] = __builtin_amdgcn_mfma_f32_16x16x32_bf16(pf, vf, oacc[db], 0,0,0);
    }
  }

  size_t obase = ((size_t)(b*2048 + qt*64 + w*16))*C + h*64;
  #pragma unroll
  for (int db=0; db<4; ++db)
    #pragma unroll
    for (int r=0;r<4;++r)
      o[obase + (size_t)(g*4+r)*C + db*16 + lrow] = f2b(oacc[db][r] / lrun[r]);
}

// ---------------- launch ----------------
extern "C" void kernel_launch(void* const* d_in, const int* in_sizes, int n_in,
                              void* d_out, int out_size, void* d_ws, size_t ws_size,
                              hipStream_t stream) {
  (void)in_sizes; (void)n_in; (void)out_size; (void)ws_size;
  const float* x    = (const float*)d_in[0];
  const float* ln1w = (const float*)d_in[1];
  const float* ln1b = (const float*)d_in[2];
  const float* ln2w = (const float*)d_in[3];
  const float* ln2b = (const float*)d_in[4];
  const float* wq   = (const float*)d_in[5];
  const float* bq   = (const float*)d_in[6];
  const float* wk   = (const float*)d_in[7];
  const float* bk   = (const float*)d_in[8];
  const float* wv   = (const float*)d_in[9];
  const float* bv   = (const float*)d_in[10];
  const float* wo   = (const float*)d_in[11];
  const float* bo   = (const float*)d_in[12];
  const float* w1   = (const float*)d_in[13];
  const float* b1   = (const float*)d_in[14];
  const float* w2   = (const float*)d_in[15];
  const float* b2   = (const float*)d_in[16];

  char* ws = (char*)d_ws;
  const size_t MB = 1u<<20;
  bf16* wqT = (bf16*)(ws + 0*MB);
  bf16* wkT = (bf16*)(ws + 2*MB);
  bf16* wvT = (bf16*)(ws + 4*MB);
  bf16* woT = (bf16*)(ws + 6*MB);
  bf16* w1T = (bf16*)(ws + 8*MB);    // [4096,1024] bf16
  bf16* w2T = (bf16*)(ws + 16*MB);   // [1024,4096] bf16
  bf16* qb  = (bf16*)(ws + 24*MB);
  bf16* kb  = (bf16*)(ws + 32*MB);
  bf16* vb  = (bf16*)(ws + 40*MB);
  bf16* ao  = (bf16*)(ws + 48*MB);
  float* x1 = (float*)(ws + 56*MB);  // 16 MB f32
  bf16* lnb = (bf16*)(ws + 72*MB);
  bf16* h1  = (bf16*)(ws + 24*MB);   // reuse q/k/v/ao region after attn proj

  dim3 tpb(32,8);
  transpose_k<<<dim3(32,32),  tpb,0,stream>>>(wq, wqT, 1024,1024);
  transpose_k<<<dim3(32,32),  tpb,0,stream>>>(wk, wkT, 1024,1024);
  transpose_k<<<dim3(32,32),  tpb,0,stream>>>(wv, wvT, 1024,1024);
  transpose_k<<<dim3(32,32),  tpb,0,stream>>>(wo, woT, 1024,1024);
  transpose_k<<<dim3(128,32), tpb,0,stream>>>(w1, w1T, 1024,4096);
  transpose_k<<<dim3(32,128), tpb,0,stream>>>(w2, w2T, 4096,1024);

  ln_k<<<4096,256,0,stream>>>(x, ln1w, ln1b, lnb);
  gemm_bt<0><<<dim3(8,32),256,0,stream>>>(lnb, wqT, bq, nullptr, qb, 4096,1024,1024);
  gemm_bt<0><<<dim3(8,32),256,0,stream>>>(lnb, wkT, bk, nullptr, kb, 4096,1024,1024);
  gemm_bt<0><<<dim3(8,32),256,0,stream>>>(lnb, wvT, bv, nullptr, vb, 4096,1024,1024);
  attn_k<<<dim3(32,16,2),256,0,stream>>>(qb, kb, vb, ao);
  gemm_bt<2><<<dim3(8,32),256,0,stream>>>(ao, woT, bo, x, x1, 4096,1024,1024);
  ln_k<<<4096,256,0,stream>>>(x1, ln2w, ln2b, lnb);
  gemm_bt<1><<<dim3(32,32),256,0,stream>>>(lnb, w1T, b1, nullptr, h1, 4096,4096,1024);
  gemm_bt<2><<<dim3(8,32),256,0,stream>>>(h1, w2T, b2, x1, (float*)d_out, 4096,1024,4096);
}